// Round 3
// baseline (77.332 us; speedup 1.0000x reference)
//
#include <hip/hip_runtime.h>

// r[b,n,o] = b2[o] + sum_h W2[h,o] * (1/N) * sum_m relu(u[b,m,h] + v[b,n,h])
//   u[m,h] =  x_m . W1[0:2,h] + y_m . W1[2:4,h]
//   v[n,h] = -x_n . W1[0:2,h] + y_n . W1[4:6,h] + b1[h]
// relu trick: sum_m relu(u+v) = 0.5*( sum_m |u+v| + Su + N*v ),
//   Su[h] = Sxx*W1[0,h]+Sxy*W1[1,h]+Syx*W1[2,h]+Syy*W1[3,h]
//
// Round-3 restructure: main loop reads UNIQUE u per lane (no 16-way broadcast
// waste). Lane = (ms = lane>>2 in [0,16), c = lane&3 channel group). Wave =
// (mh = wave>>2 m-half of 512, ng = wave&3 n-group of 8). Each lane holds
// v[8]/s[8] float4 registers; 1 ds_read_b128 feeds 64 VALU instrs.
// Per CU: 256 b128 reads (~3.1K cyc) vs VALU ~8.2K cyc -> VALU-bound ~3.5us.

constexpr int NN = 1024;

// LDS float offsets
#define SPILL_STRIDE 528              // 512 + 16 pad -> 2-way bank alias (free)
#define V_OFF   16896                 // vseg[32][16]
#define W2_OFF  17408                 // W2[16][16]
#define B2_OFF  17664                 // b2[16]
#define W1_OFF  17680                 // W1 rows 0..3 [4][16]
#define BS_OFF  17744                 // batch-sum partials [8][4]
#define SF_OFF  17776                 // s_final[32][16]
#define LDS_FLOATS 18288

__global__ __launch_bounds__(512, 2) void te_enc(
    const float* __restrict__ x_ctx,
    const float* __restrict__ y_ctx,
    const float* __restrict__ W1,
    const float* __restrict__ b1,
    const float* __restrict__ W2,
    const float* __restrict__ b2,
    float* __restrict__ out)
{
    __shared__ float lds[LDS_FLOATS];

    const int t    = threadIdx.x;
    const int wave = t >> 6;
    const int lane = t & 63;
    const int b    = blockIdx.x >> 5;
    const int n0   = (blockIdx.x & 31) << 5;

    // ---- staging: small constants ----
    if (t < 256) lds[W2_OFF + t] = W2[t];
    if (t < 16)  lds[B2_OFF + t] = b2[t];
    if (t < 64)  lds[W1_OFF + t] = W1[t];   // rows 0..3

    // ---- vseg[nt][h]: v for this block's 32 n ----
    {
        const int nt = t >> 4, h = t & 15;
        const int n  = n0 + nt;
        const float2 xn = *(const float2*)(x_ctx + (b * NN + n) * 2);
        const float2 yn = *(const float2*)(y_ctx + (b * NN + n) * 2);
        lds[V_OFF + nt * 16 + h] =
            b1[h] - xn.x * W1[h] - xn.y * W1[16 + h]
                  + yn.x * W1[64 + h] + yn.y * W1[80 + h];
    }

    // ---- u[m][0..15] for all 1024 m -> lds[0,16384) ----
    {
        const int g = t & 3, mm = t >> 2;
        const float4 w10 = *(const float4*)(W1 +  0 + 4 * g);
        const float4 w11 = *(const float4*)(W1 + 16 + 4 * g);
        const float4 w12 = *(const float4*)(W1 + 32 + 4 * g);
        const float4 w13 = *(const float4*)(W1 + 48 + 4 * g);
        #pragma unroll
        for (int rep = 0; rep < 8; ++rep) {
            const int m = rep * 128 + mm;
            const float2 xm = *(const float2*)(x_ctx + (b * NN + m) * 2);
            const float2 ym = *(const float2*)(y_ctx + (b * NN + m) * 2);
            float4 u;
            u.x = xm.x*w10.x + xm.y*w11.x + ym.x*w12.x + ym.y*w13.x;
            u.y = xm.x*w10.y + xm.y*w11.y + ym.x*w12.y + ym.y*w13.y;
            u.z = xm.x*w10.z + xm.y*w11.z + ym.x*w12.z + ym.y*w13.z;
            u.w = xm.x*w10.w + xm.y*w11.w + ym.x*w12.w + ym.y*w13.w;
            *(float4*)(lds + m * 16 + 4 * g) = u;
        }
    }

    // ---- batch sums (for Su) -> bs[wave][4] ----
    {
        const float4 xa = *(const float4*)(x_ctx + b * 2048 + t * 4);
        const float4 ya = *(const float4*)(y_ctx + b * 2048 + t * 4);
        float sxx = xa.x + xa.z;
        float sxy = xa.y + xa.w;
        float syx = ya.x + ya.z;
        float syy = ya.y + ya.w;
        #pragma unroll
        for (int off = 32; off > 0; off >>= 1) {
            sxx += __shfl_down(sxx, off);
            sxy += __shfl_down(sxy, off);
            syx += __shfl_down(syx, off);
            syy += __shfl_down(syy, off);
        }
        if (lane == 0) {
            float4 bsv = {sxx, sxy, syx, syy};
            *(float4*)(lds + BS_OFF + wave * 4) = bsv;
        }
    }
    __syncthreads();

    // ---- per-lane v[8] from vseg (broadcast reads, setup only) ----
    const int c  = lane & 3;
    const int ms = lane >> 2;
    const int ng = wave & 3;
    const int mh = wave >> 2;
    float4 v[8];
    #pragma unroll
    for (int j = 0; j < 8; ++j)
        v[j] = *(const float4*)(lds + V_OFF + (ng * 8 + j) * 16 + 4 * c);

    // ---- main loop: 512 m per wave, 16 m per iteration ----
    float4 s[8];
    #pragma unroll
    for (int j = 0; j < 8; ++j) s[j] = make_float4(0.f, 0.f, 0.f, 0.f);

    const float* up = lds + (mh * 512 + ms) * 16 + 4 * c;
    #pragma unroll 4
    for (int i = 0; i < 32; ++i) {
        const float4 u = *(const float4*)(up + i * 256);
        #pragma unroll
        for (int j = 0; j < 8; ++j) {
            s[j].x += fabsf(u.x + v[j].x);
            s[j].y += fabsf(u.y + v[j].y);
            s[j].z += fabsf(u.z + v[j].z);
            s[j].w += fabsf(u.w + v[j].w);
        }
    }
    __syncthreads();   // all u reads done; lds[0,16896) reusable as spill

    // ---- spill partials: spill[slice][nt*16 + 4c] ----
    {
        const int slice = mh * 16 + ms;
        float* sp = lds + slice * SPILL_STRIDE + 4 * c;
        #pragma unroll
        for (int j = 0; j < 8; ++j)
            *(float4*)(sp + (ng * 8 + j) * 16) = s[j];
    }
    __syncthreads();

    // ---- reduce 32 slices + relu-identity (threads 0..127) ----
    if (t < 128) {
        const int nt = t >> 2, h4 = t & 3, hh = h4 * 4;
        float4 acc = {0.f, 0.f, 0.f, 0.f};
        #pragma unroll
        for (int sl = 0; sl < 32; ++sl) {
            const float4 q = *(const float4*)(lds + sl * SPILL_STRIDE + nt * 16 + hh);
            acc.x += q.x; acc.y += q.y; acc.z += q.z; acc.w += q.w;
        }
        float4 bsum = {0.f, 0.f, 0.f, 0.f};
        #pragma unroll
        for (int w = 0; w < 8; ++w) {
            const float4 q = *(const float4*)(lds + BS_OFF + w * 4);
            bsum.x += q.x; bsum.y += q.y; bsum.z += q.z; bsum.w += q.w;
        }
        const float* w1r = lds + W1_OFF;
        float4 su;
        su.x = bsum.x*w1r[hh  ] + bsum.y*w1r[16+hh  ] + bsum.z*w1r[32+hh  ] + bsum.w*w1r[48+hh  ];
        su.y = bsum.x*w1r[hh+1] + bsum.y*w1r[16+hh+1] + bsum.z*w1r[32+hh+1] + bsum.w*w1r[48+hh+1];
        su.z = bsum.x*w1r[hh+2] + bsum.y*w1r[16+hh+2] + bsum.z*w1r[32+hh+2] + bsum.w*w1r[48+hh+2];
        su.w = bsum.x*w1r[hh+3] + bsum.y*w1r[16+hh+3] + bsum.z*w1r[32+hh+3] + bsum.w*w1r[48+hh+3];
        const float4 vv = *(const float4*)(lds + V_OFF + nt * 16 + hh);
        const float k = 0.5f / 1024.0f;
        float4 r;
        r.x = (acc.x + su.x) * k + 0.5f * vv.x;
        r.y = (acc.y + su.y) * k + 0.5f * vv.y;
        r.z = (acc.z + su.z) * k + 0.5f * vv.z;
        r.w = (acc.w + su.w) * k + 0.5f * vv.w;
        *(float4*)(lds + SF_OFF + nt * 16 + hh) = r;
    }
    __syncthreads();

    // ---- W2 epilogue, coalesced store ----
    {
        const int j = t >> 4;      // n within tile
        const int o = t & 15;      // output channel
        const float* sf = lds + SF_OFF + j * 16;
        const float* w2 = lds + W2_OFF;
        float acc = lds[B2_OFF + o];
        #pragma unroll
        for (int h = 0; h < 16; ++h)
            acc += sf[h] * w2[h * 16 + o];
        out[(b * NN + n0 + j) * 16 + o] = acc;
    }
}

extern "C" void kernel_launch(void* const* d_in, const int* in_sizes, int n_in,
                              void* d_out, int out_size, void* d_ws, size_t ws_size,
                              hipStream_t stream) {
    const float* x_ctx = (const float*)d_in[0];
    const float* y_ctx = (const float*)d_in[1];
    // d_in[2] = x_trg : unused by the reference computation
    const float* W1 = (const float*)d_in[3];
    const float* b1 = (const float*)d_in[4];
    const float* W2 = (const float*)d_in[5];
    const float* b2 = (const float*)d_in[6];
    float* out = (float*)d_out;

    te_enc<<<256, 512, 0, stream>>>(x_ctx, y_ctx, W1, b1, W2, b2, out);
}